// Round 11
// baseline (305.556 us; speedup 1.0000x reference)
//
#include <hip/hip_runtime.h>

typedef unsigned short u16;
typedef __attribute__((ext_vector_type(8))) __bf16 bf16x8;
typedef __attribute__((ext_vector_type(4))) float f32x4;

__device__ __forceinline__ float sigf(float z) {
    return 1.f / (1.f + __expf(-z));
}

__device__ __forceinline__ bf16x8 cvt8(f32x4 lo, f32x4 hi) {
    bf16x8 w;
    w[0] = (__bf16)lo.x; w[1] = (__bf16)lo.y; w[2] = (__bf16)lo.z; w[3] = (__bf16)lo.w;
    w[4] = (__bf16)hi.x; w[5] = (__bf16)hi.y; w[6] = (__bf16)hi.z; w[7] = (__bf16)hi.w;
    return w;
}

// ---------------- single-kernel fused SRU-LSTM cell ----------------
// No convert kernel, no blob, no workspace: staging is direct
// {f32 global load -> bf16 cast -> XOR-swizzled ds_write}, with ALL staging
// state dead before the barrier (r9/r10 post-mortem: any register held live
// across __syncthreads beyond acc spills -> WRITE_SIZE 45-47 MB, 14 MB
// scratch. Here loads+cvt+writes complete in-phase; barrier carries only
// lgkm, exactly as r0/r7's barrier carried vmcnt).
// Geometry/compute/epilogue = r7 verbatim (8 waves, 128m x 64j x 5seg,
// per-wave 32x32, acc 80, 56 KB LDS, 2-barrier single-buffer loop -- best
// bench total 222.0us, VGPR 60, zero spill).
// LDS content bit-identical to r7: write dest-swizzle LDS[row][g^(row&7)] =
// global[row][g] is the XOR-involution of r7's source-swizzle; the verified
// read side (sw = (((kk>>3)+fq)^r7)<<3) is untouched. A-path numerics ==
// r10's B-path (passed absmax 0.0234375); W-path == r10's W-path.
__global__ __launch_bounds__(512) void srulstm_one(
    const float* __restrict__ xf, const float* __restrict__ hf,
    const float* __restrict__ c_prev,
    const float* __restrict__ Wi, const float* __restrict__ Wf,
    const float* __restrict__ Wo, const float* __restrict__ Wxs,
    const float* __restrict__ Wxg, const float* __restrict__ Whg,
    const float* __restrict__ bi, const float* __restrict__ bfv,
    const float* __restrict__ bo, const float* __restrict__ bxs,
    const float* __restrict__ bxg, const float* __restrict__ bhg,
    float* __restrict__ out)
{
    __shared__ __align__(16) u16 As[128 * 64];       // 16 KB
    __shared__ __align__(16) u16 Bs[5 * 64 * 64];    // 40 KB

    const int t = threadIdx.x;
    const int j0 = blockIdx.x * 64;    // 16 j-slices
    const int m0 = blockIdx.y * 128;   // 32 m-tiles

    const int lane = t & 63;
    const int wave = t >> 6;           // 0..7
    const int wm = (wave >> 1) << 5;   // 0/32/64/96
    const int wn = (wave & 1) << 5;    // 0/32
    const int fr = lane & 15;
    const int fq = lane >> 4;
    const int r7 = fr & 7;

    const int er = t >> 3;             // staging row (0..63)
    const int g8 = t & 7;              // staging granule (8 elems)
    const int gsw = ((g8 ^ (er & 7)) << 3);   // swizzled LDS granule offset

    // per-thread staging source bases (linear granule g8; swizzle on LDS dest)
    const float* pA  = (const float*)0;  // set per k-half below
    const float* pWi  = Wi  + (long)(j0 + er) * 2048 + g8 * 8;
    const float* pWf  = Wf  + (long)(j0 + er) * 2048 + g8 * 8;
    const float* pWo  = Wo  + (long)(j0 + er) * 2048 + g8 * 8;
    const float* pWxg = Wxg + (long)(j0 + er) * 1024 + g8 * 8;
    const float* pWhg = Whg + (long)(j0 + er) * 1024 + g8 * 8;
    const float* pWxs = Wxs + (long)(j0 + er) * 1024 + g8 * 8;
    const float* pAx = xf + (long)(m0 + er) * 1024 + g8 * 8;
    const float* pAh = hf + (long)(m0 + er) * 1024 + g8 * 8;

    f32x4 acc[5][2][2] = {};           // [seg][mi][ni] -- 80 f32/thread

    for (int k0 = 0; k0 < 2048; k0 += 64) {
        const int kc = k0 & 1023;
        // ---- staging: all loads issued, then cvt+write; nothing survives
        //      the barrier (spill-safe). ----
        pA = (k0 < 1024) ? pAx : pAh;
        f32x4 va0 = *(const f32x4*)(pA + kc);
        f32x4 va1 = *(const f32x4*)(pA + kc + 4);
        f32x4 va2 = *(const f32x4*)(pA + kc + 65536);      // +64 rows
        f32x4 va3 = *(const f32x4*)(pA + kc + 65536 + 4);
        f32x4 vb00 = *(const f32x4*)(pWi + k0);
        f32x4 vb01 = *(const f32x4*)(pWi + k0 + 4);
        f32x4 vb10 = *(const f32x4*)(pWf + k0);
        f32x4 vb11 = *(const f32x4*)(pWf + k0 + 4);
        f32x4 vb20 = *(const f32x4*)(pWo + k0);
        f32x4 vb21 = *(const f32x4*)(pWo + k0 + 4);
        const float* w3p = (k0 < 1024) ? (pWxg + k0) : (pWhg + (k0 - 1024));
        f32x4 vb30 = *(const f32x4*)(w3p);
        f32x4 vb31 = *(const f32x4*)(w3p + 4);

        *(bf16x8*)(As + er * 64 + gsw)        = cvt8(va0, va1);
        *(bf16x8*)(As + (64 + er) * 64 + gsw) = cvt8(va2, va3);
        *(bf16x8*)(Bs +         er * 64 + gsw) = cvt8(vb00, vb01);
        *(bf16x8*)(Bs + 4096  + er * 64 + gsw) = cvt8(vb10, vb11);
        *(bf16x8*)(Bs + 8192  + er * 64 + gsw) = cvt8(vb20, vb21);
        *(bf16x8*)(Bs + 12288 + er * 64 + gsw) = cvt8(vb30, vb31);
        if (k0 < 1024) {               // seg 4 (Wxs) exists only for k<1024
            f32x4 vb40 = *(const f32x4*)(pWxs + k0);
            f32x4 vb41 = *(const f32x4*)(pWxs + k0 + 4);
            *(bf16x8*)(Bs + 16384 + er * 64 + gsw) = cvt8(vb40, vb41);
        }
        __syncthreads();
        // ---- compute (r7-verified fragment math, verbatim) ----
#pragma unroll
        for (int kk = 0; kk < 64; kk += 32) {
            const int sw = ((((kk >> 3) + fq) ^ r7) << 3);
            bf16x8 a[2];
#pragma unroll
            for (int mi = 0; mi < 2; ++mi)
                a[mi] = *(const bf16x8*)(As + (wm + mi * 16 + fr) * 64 + sw);
#pragma unroll
            for (int s = 0; s < 4; ++s) {
                bf16x8 b0 = *(const bf16x8*)(Bs + s * 4096 + (wn + fr) * 64 + sw);
                bf16x8 b1 = *(const bf16x8*)(Bs + s * 4096 + (wn + 16 + fr) * 64 + sw);
#pragma unroll
                for (int mi = 0; mi < 2; ++mi) {
                    acc[s][mi][0] = __builtin_amdgcn_mfma_f32_16x16x32_bf16(
                        a[mi], b0, acc[s][mi][0], 0, 0, 0);
                    acc[s][mi][1] = __builtin_amdgcn_mfma_f32_16x16x32_bf16(
                        a[mi], b1, acc[s][mi][1], 0, 0, 0);
                }
            }
            if (k0 < 1024) {
                bf16x8 b0 = *(const bf16x8*)(Bs + 16384 + (wn + fr) * 64 + sw);
                bf16x8 b1 = *(const bf16x8*)(Bs + 16384 + (wn + 16 + fr) * 64 + sw);
#pragma unroll
                for (int mi = 0; mi < 2; ++mi) {
                    acc[4][mi][0] = __builtin_amdgcn_mfma_f32_16x16x32_bf16(
                        a[mi], b0, acc[4][mi][0], 0, 0, 0);
                    acc[4][mi][1] = __builtin_amdgcn_mfma_f32_16x16x32_bf16(
                        a[mi], b1, acc[4][mi][1], 0, 0, 0);
                }
            }
        }
        __syncthreads();               // WAR: reads done before next staging
    }

    // ---- in-register LSTM epilogue (r7-verified) ----
    // C/D layout (m89): lane holds D[m=fq*4+r][n=fr]; all 5 segs aligned.
    const int orow = m0 + wm + (fq << 2);
    const int ocol = j0 + wn + fr;
#pragma unroll
    for (int ni = 0; ni < 2; ++ni) {
        const int col = ocol + ni * 16;
        const float bi_v = bi[col],  bf_v = bfv[col], bo_v = bo[col];
        const float bs_v = bxs[col], bg_v = bxg[col], bh_v = bhg[col];
#pragma unroll
        for (int mi = 0; mi < 2; ++mi) {
#pragma unroll
            for (int r = 0; r < 4; ++r) {
                const long idx = (long)(orow + mi * 16 + r) * 1024 + col;
                const float cp = c_prev[idx];
                const float i_t = sigf(acc[0][mi][ni][r] + bi_v);
                const float f_t = sigf(acc[1][mi][ni][r] + bf_v);
                const float o_t = sigf(acc[2][mi][ni][r] + bo_v);
                const float cand = acc[3][mi][ni][r] + bg_v + bh_v;
                const float s_t  = acc[4][mi][ni][r] + bs_v;
                const float g_t = tanhf(s_t * cand);
                const float c_t = f_t * cp + i_t * g_t;
                const float h_t = o_t * tanhf(c_t);
                out[idx] = h_t;                    // h_t
                out[4194304L + idx] = c_t;         // c_t
            }
        }
    }
}

extern "C" void kernel_launch(void* const* d_in, const int* in_sizes, int n_in,
                              void* d_out, int out_size, void* d_ws, size_t ws_size,
                              hipStream_t stream)
{
    float* out = (float*)d_out;

    srulstm_one<<<dim3(16, 32), dim3(512), 0, stream>>>(
        (const float*)d_in[0],  (const float*)d_in[1],  (const float*)d_in[2],
        (const float*)d_in[3],  (const float*)d_in[5],  (const float*)d_in[7],
        (const float*)d_in[9],  (const float*)d_in[11], (const float*)d_in[13],
        (const float*)d_in[4],  (const float*)d_in[6],  (const float*)d_in[8],
        (const float*)d_in[10], (const float*)d_in[12], (const float*)d_in[14],
        out);
}